// Round 1
// baseline (17534.842 us; speedup 1.0000x reference)
//
#include <hip/hip_runtime.h>

#define FD 32
#define KNB 8
#define NITER 5

__device__ __forceinline__ float sigmoidf_(float a) {
    return 1.0f / (1.0f + __expf(-a));
}
// tanh(a) = 1 - 2/(exp(2a)+1); correct limits at +/-inf via exp overflow/underflow
__device__ __forceinline__ float tanhf_(float a) {
    return 1.0f - 2.0f / (__expf(2.0f * a) + 1.0f);
}

// One thread per path. Keeps h_p row in registers across the 8 sequential GRU
// steps (h_c is frozen during the path update), then scatter-adds the final
// h_p row into agg via f32 atomics (fused segment_sum).
__global__ __launch_bounds__(256) void path_update_kernel(
    const float* __restrict__ h_c, float* __restrict__ h_p,
    const int* __restrict__ p2c,
    const float* __restrict__ Wih, const float* __restrict__ Whh,
    const float* __restrict__ bih, const float* __restrict__ bhh,
    float* __restrict__ agg, int P)
{
    int p = blockIdx.x * blockDim.x + threadIdx.x;
    if (p >= P) return;

    float h[FD];
    const float4* hp4 = (const float4*)(h_p + (size_t)p * FD);
    #pragma unroll
    for (int i = 0; i < FD / 4; i++) {
        float4 v = hp4[i];
        h[4*i] = v.x; h[4*i+1] = v.y; h[4*i+2] = v.z; h[4*i+3] = v.w;
    }

    int idx[KNB];
    const int4* pi = (const int4*)(p2c + (size_t)p * KNB);
    int4 i0 = pi[0], i1 = pi[1];
    idx[0]=i0.x; idx[1]=i0.y; idx[2]=i0.z; idx[3]=i0.w;
    idx[4]=i1.x; idx[5]=i1.y; idx[6]=i1.z; idx[7]=i1.w;

    for (int k = 0; k < KNB; k++) {
        float x[FD];
        const float4* xr = (const float4*)(h_c + (size_t)idx[k] * FD);
        #pragma unroll
        for (int i = 0; i < FD / 4; i++) {
            float4 v = xr[i];
            x[4*i] = v.x; x[4*i+1] = v.y; x[4*i+2] = v.z; x[4*i+3] = v.w;
        }

        float hn[FD];
        #pragma unroll 4
        for (int j = 0; j < FD; j++) {
            // 6 independent dot-product chains -> ILP for the FMA pipe.
            float air = bih[j],        ahr = bhh[j];
            float aiz = bih[FD + j],   ahz = bhh[FD + j];
            float ain = bih[2*FD + j], ahn = bhh[2*FD + j];
            #pragma unroll
            for (int i = 0; i < FD; i++) {
                // weight addresses are wave-uniform -> s_load + v_fmac v,s,v
                air = fmaf(Wih[j*FD + i],        x[i], air);
                ahr = fmaf(Whh[j*FD + i],        h[i], ahr);
                aiz = fmaf(Wih[(FD + j)*FD + i], x[i], aiz);
                ahz = fmaf(Whh[(FD + j)*FD + i], h[i], ahz);
                ain = fmaf(Wih[(2*FD + j)*FD + i], x[i], ain);
                ahn = fmaf(Whh[(2*FD + j)*FD + i], h[i], ahn);
            }
            float r = sigmoidf_(air + ahr);
            float z = sigmoidf_(aiz + ahz);
            float n = tanhf_(ain + r * ahn);
            hn[j] = (1.0f - z) * n + z * h[j];
        }
        #pragma unroll
        for (int j = 0; j < FD; j++) h[j] = hn[j];
    }

    float4* hpw = (float4*)(h_p + (size_t)p * FD);
    #pragma unroll
    for (int i = 0; i < FD / 4; i++) {
        float4 v;
        v.x = h[4*i]; v.y = h[4*i+1]; v.z = h[4*i+2]; v.w = h[4*i+3];
        hpw[i] = v;
    }

    // fused segment_sum: each edge (p,k) adds h_p[p] into agg[idx[k]]
    #pragma unroll
    for (int k = 0; k < KNB; k++) {
        float* ar = agg + (size_t)idx[k] * FD;
        #pragma unroll
        for (int i = 0; i < FD; i++) atomicAdd(ar + i, h[i]);
    }
}

// One thread per channel: h_c = GRU2(agg, h_c) in place.
__global__ __launch_bounds__(256) void channel_update_kernel(
    const float* __restrict__ agg, float* __restrict__ h_c,
    const float* __restrict__ Wih, const float* __restrict__ Whh,
    const float* __restrict__ bih, const float* __restrict__ bhh, int C)
{
    int c = blockIdx.x * blockDim.x + threadIdx.x;
    if (c >= C) return;

    float h[FD], x[FD];
    const float4* hr = (const float4*)(h_c + (size_t)c * FD);
    const float4* xr = (const float4*)(agg + (size_t)c * FD);
    #pragma unroll
    for (int i = 0; i < FD / 4; i++) {
        float4 v = hr[i];
        h[4*i] = v.x; h[4*i+1] = v.y; h[4*i+2] = v.z; h[4*i+3] = v.w;
        float4 w = xr[i];
        x[4*i] = w.x; x[4*i+1] = w.y; x[4*i+2] = w.z; x[4*i+3] = w.w;
    }

    float hn[FD];
    #pragma unroll 4
    for (int j = 0; j < FD; j++) {
        float air = bih[j],        ahr = bhh[j];
        float aiz = bih[FD + j],   ahz = bhh[FD + j];
        float ain = bih[2*FD + j], ahn = bhh[2*FD + j];
        #pragma unroll
        for (int i = 0; i < FD; i++) {
            air = fmaf(Wih[j*FD + i],        x[i], air);
            ahr = fmaf(Whh[j*FD + i],        h[i], ahr);
            aiz = fmaf(Wih[(FD + j)*FD + i], x[i], aiz);
            ahz = fmaf(Whh[(FD + j)*FD + i], h[i], ahz);
            ain = fmaf(Wih[(2*FD + j)*FD + i], x[i], ain);
            ahn = fmaf(Whh[(2*FD + j)*FD + i], h[i], ahn);
        }
        float r = sigmoidf_(air + ahr);
        float z = sigmoidf_(aiz + ahz);
        float n = tanhf_(ain + r * ahn);
        hn[j] = (1.0f - z) * n + z * h[j];
    }

    float4* hw = (float4*)(h_c + (size_t)c * FD);
    #pragma unroll
    for (int i = 0; i < FD / 4; i++) {
        float4 v;
        v.x = hn[4*i]; v.y = hn[4*i+1]; v.z = hn[4*i+2]; v.w = hn[4*i+3];
        hw[i] = v;
    }
}

extern "C" void kernel_launch(void* const* d_in, const int* in_sizes, int n_in,
                              void* d_out, int out_size, void* d_ws, size_t ws_size,
                              hipStream_t stream) {
    const float* paths    = (const float*)d_in[0];
    const float* channels = (const float*)d_in[1];
    const int*   p2c      = (const int*)d_in[2];
    const float* Wih1 = (const float*)d_in[3];
    const float* Whh1 = (const float*)d_in[4];
    const float* bih1 = (const float*)d_in[5];
    const float* bhh1 = (const float*)d_in[6];
    const float* Wih2 = (const float*)d_in[7];
    const float* Whh2 = (const float*)d_in[8];
    const float* bih2 = (const float*)d_in[9];
    const float* bhh2 = (const float*)d_in[10];

    const int P = in_sizes[0] / FD;   // 200000
    const int C = in_sizes[1] / FD;   // 50000

    float* h_p = (float*)d_out;                  // [P*FD]
    float* h_c = h_p + (size_t)P * FD;           // [C*FD]
    float* agg = (float*)d_ws;                   // [C*FD] scratch (6.4 MB)

    // initialize state from inputs (fresh every call; inputs never mutated)
    hipMemcpyAsync(h_p, paths,    (size_t)P * FD * sizeof(float),
                   hipMemcpyDeviceToDevice, stream);
    hipMemcpyAsync(h_c, channels, (size_t)C * FD * sizeof(float),
                   hipMemcpyDeviceToDevice, stream);

    dim3 pb(256), pg((P + 255) / 256);
    dim3 cb(256), cg((C + 255) / 256);

    for (int it = 0; it < NITER; it++) {
        hipMemsetAsync(agg, 0, (size_t)C * FD * sizeof(float), stream);
        path_update_kernel<<<pg, pb, 0, stream>>>(h_c, h_p, p2c,
                                                  Wih1, Whh1, bih1, bhh1,
                                                  agg, P);
        channel_update_kernel<<<cg, cb, 0, stream>>>(agg, h_c,
                                                     Wih2, Whh2, bih2, bhh2, C);
    }
}

// Round 2
// 5369.108 us; speedup vs baseline: 3.2659x; 3.2659x over previous
//
#include <hip/hip_runtime.h>

#define FD 32
#define KNB 8
#define NITER 5

__device__ __forceinline__ float sigmoidf_(float a) {
    return 1.0f / (1.0f + __expf(-a));
}
// tanh(a) = 1 - 2/(exp(2a)+1); correct limits at +/-inf via exp overflow/underflow
__device__ __forceinline__ float tanhf_(float a) {
    return 1.0f - 2.0f / (__expf(2.0f * a) + 1.0f);
}

// ---------------- CSR build (once per launch; edge list is static) ----------

__global__ __launch_bounds__(256) void count_edges_kernel(
    const int* __restrict__ p2c, int* __restrict__ counts, int E)
{
    int e = blockIdx.x * blockDim.x + threadIdx.x;
    if (e < E) atomicAdd(&counts[p2c[e]], 1);
}

// single block, 1024 threads: exclusive scan of counts -> offsets, cursor
__global__ __launch_bounds__(1024) void scan_offsets_kernel(
    const int* __restrict__ counts, int* __restrict__ offsets,
    int* __restrict__ cursor, int C)
{
    __shared__ int part[1024];
    int t = threadIdx.x;
    int chunk = (C + 1023) >> 10;
    int base = t * chunk;
    int end = base + chunk; if (end > C) end = C;
    int s = 0;
    for (int i = base; i < end; i++) s += counts[i];
    part[t] = s;
    __syncthreads();
    // Hillis-Steele inclusive scan over 1024 partials
    for (int d = 1; d < 1024; d <<= 1) {
        int v = (t >= d) ? part[t - d] : 0;
        __syncthreads();
        part[t] += v;
        __syncthreads();
    }
    int run = (t == 0) ? 0 : part[t - 1];
    for (int i = base; i < end; i++) {
        offsets[i] = run;
        cursor[i] = run;
        run += counts[i];
    }
    if (t == 1023) offsets[C] = part[1023];
}

__global__ __launch_bounds__(256) void fill_elist_kernel(
    const int* __restrict__ p2c, int* __restrict__ cursor,
    int* __restrict__ elist, int E)
{
    int e = blockIdx.x * blockDim.x + threadIdx.x;
    if (e < E) {
        int c = p2c[e];
        int pos = atomicAdd(&cursor[c], 1);
        elist[pos] = e >> 3;   // path id (KNB == 8)
    }
}

// ---------------- per-iteration kernels -------------------------------------

// One thread per path. h_p row lives in registers across the 8 sequential GRU
// steps (h_c frozen during path update).
__global__ __launch_bounds__(256) void path_update_kernel(
    const float* __restrict__ h_c, float* __restrict__ h_p,
    const int* __restrict__ p2c,
    const float* __restrict__ Wih, const float* __restrict__ Whh,
    const float* __restrict__ bih, const float* __restrict__ bhh, int P)
{
    int p = blockIdx.x * blockDim.x + threadIdx.x;
    if (p >= P) return;

    float h[FD];
    const float4* hp4 = (const float4*)(h_p + (size_t)p * FD);
    #pragma unroll
    for (int i = 0; i < FD / 4; i++) {
        float4 v = hp4[i];
        h[4*i] = v.x; h[4*i+1] = v.y; h[4*i+2] = v.z; h[4*i+3] = v.w;
    }

    int idx[KNB];
    const int4* pi = (const int4*)(p2c + (size_t)p * KNB);
    int4 i0 = pi[0], i1 = pi[1];
    idx[0]=i0.x; idx[1]=i0.y; idx[2]=i0.z; idx[3]=i0.w;
    idx[4]=i1.x; idx[5]=i1.y; idx[6]=i1.z; idx[7]=i1.w;

    for (int k = 0; k < KNB; k++) {
        float x[FD];
        const float4* xr = (const float4*)(h_c + (size_t)idx[k] * FD);
        #pragma unroll
        for (int i = 0; i < FD / 4; i++) {
            float4 v = xr[i];
            x[4*i] = v.x; x[4*i+1] = v.y; x[4*i+2] = v.z; x[4*i+3] = v.w;
        }

        float hn[FD];
        #pragma unroll 4
        for (int j = 0; j < FD; j++) {
            float air = bih[j],        ahr = bhh[j];
            float aiz = bih[FD + j],   ahz = bhh[FD + j];
            float ain = bih[2*FD + j], ahn = bhh[2*FD + j];
            #pragma unroll
            for (int i = 0; i < FD; i++) {
                air = fmaf(Wih[j*FD + i],          x[i], air);
                ahr = fmaf(Whh[j*FD + i],          h[i], ahr);
                aiz = fmaf(Wih[(FD + j)*FD + i],   x[i], aiz);
                ahz = fmaf(Whh[(FD + j)*FD + i],   h[i], ahz);
                ain = fmaf(Wih[(2*FD + j)*FD + i], x[i], ain);
                ahn = fmaf(Whh[(2*FD + j)*FD + i], h[i], ahn);
            }
            float r = sigmoidf_(air + ahr);
            float z = sigmoidf_(aiz + ahz);
            float n = tanhf_(ain + r * ahn);
            hn[j] = (1.0f - z) * n + z * h[j];
        }
        #pragma unroll
        for (int j = 0; j < FD; j++) h[j] = hn[j];
    }

    float4* hpw = (float4*)(h_p + (size_t)p * FD);
    #pragma unroll
    for (int i = 0; i < FD / 4; i++) {
        float4 v;
        v.x = h[4*i]; v.y = h[4*i+1]; v.z = h[4*i+2]; v.w = h[4*i+3];
        hpw[i] = v;
    }
}

// Atomic-scatter fallback tail (only used if ws too small for CSR)
__global__ __launch_bounds__(256) void scatter_agg_atomic_kernel(
    const float* __restrict__ h_p, const int* __restrict__ p2c,
    float* __restrict__ agg, int P)
{
    int p = blockIdx.x * blockDim.x + threadIdx.x;
    if (p >= P) return;
    const float* hr = h_p + (size_t)p * FD;
    #pragma unroll
    for (int k = 0; k < KNB; k++) {
        int c = p2c[(size_t)p * KNB + k];
        float* ar = agg + (size_t)c * FD;
        #pragma unroll
        for (int i = 0; i < FD; i++) atomicAdd(ar + i, hr[i]);
    }
}

// 32 lanes per channel (lane -> feature); coalesced 128B row reads, no atomics.
__global__ __launch_bounds__(256) void gather_agg_kernel(
    const float* __restrict__ h_p, const int* __restrict__ offsets,
    const int* __restrict__ elist, float* __restrict__ agg, int C)
{
    int tid = blockIdx.x * blockDim.x + threadIdx.x;
    int c = tid >> 5;
    int feat = tid & 31;
    if (c >= C) return;
    int s = offsets[c], e = offsets[c + 1];
    float acc0 = 0.f, acc1 = 0.f;
    int i = s;
    for (; i + 2 <= e; i += 2) {
        acc0 += h_p[(size_t)elist[i]     * FD + feat];
        acc1 += h_p[(size_t)elist[i + 1] * FD + feat];
    }
    if (i < e) acc0 += h_p[(size_t)elist[i] * FD + feat];
    agg[(size_t)c * FD + feat] = acc0 + acc1;
}

// One thread per channel: h_c = GRU2(agg, h_c) in place.
__global__ __launch_bounds__(256) void channel_update_kernel(
    const float* __restrict__ agg, float* __restrict__ h_c,
    const float* __restrict__ Wih, const float* __restrict__ Whh,
    const float* __restrict__ bih, const float* __restrict__ bhh, int C)
{
    int c = blockIdx.x * blockDim.x + threadIdx.x;
    if (c >= C) return;

    float h[FD], x[FD];
    const float4* hr = (const float4*)(h_c + (size_t)c * FD);
    const float4* xr = (const float4*)(agg + (size_t)c * FD);
    #pragma unroll
    for (int i = 0; i < FD / 4; i++) {
        float4 v = hr[i];
        h[4*i] = v.x; h[4*i+1] = v.y; h[4*i+2] = v.z; h[4*i+3] = v.w;
        float4 w = xr[i];
        x[4*i] = w.x; x[4*i+1] = w.y; x[4*i+2] = w.z; x[4*i+3] = w.w;
    }

    float hn[FD];
    #pragma unroll 4
    for (int j = 0; j < FD; j++) {
        float air = bih[j],        ahr = bhh[j];
        float aiz = bih[FD + j],   ahz = bhh[FD + j];
        float ain = bih[2*FD + j], ahn = bhh[2*FD + j];
        #pragma unroll
        for (int i = 0; i < FD; i++) {
            air = fmaf(Wih[j*FD + i],          x[i], air);
            ahr = fmaf(Whh[j*FD + i],          h[i], ahr);
            aiz = fmaf(Wih[(FD + j)*FD + i],   x[i], aiz);
            ahz = fmaf(Whh[(FD + j)*FD + i],   h[i], ahz);
            ain = fmaf(Wih[(2*FD + j)*FD + i], x[i], ain);
            ahn = fmaf(Whh[(2*FD + j)*FD + i], h[i], ahn);
        }
        float r = sigmoidf_(air + ahr);
        float z = sigmoidf_(aiz + ahz);
        float n = tanhf_(ain + r * ahn);
        hn[j] = (1.0f - z) * n + z * h[j];
    }

    float4* hw = (float4*)(h_c + (size_t)c * FD);
    #pragma unroll
    for (int i = 0; i < FD / 4; i++) {
        float4 v;
        v.x = hn[4*i]; v.y = hn[4*i+1]; v.z = hn[4*i+2]; v.w = hn[4*i+3];
        hw[i] = v;
    }
}

extern "C" void kernel_launch(void* const* d_in, const int* in_sizes, int n_in,
                              void* d_out, int out_size, void* d_ws, size_t ws_size,
                              hipStream_t stream) {
    const float* paths    = (const float*)d_in[0];
    const float* channels = (const float*)d_in[1];
    const int*   p2c      = (const int*)d_in[2];
    const float* Wih1 = (const float*)d_in[3];
    const float* Whh1 = (const float*)d_in[4];
    const float* bih1 = (const float*)d_in[5];
    const float* bhh1 = (const float*)d_in[6];
    const float* Wih2 = (const float*)d_in[7];
    const float* Whh2 = (const float*)d_in[8];
    const float* bih2 = (const float*)d_in[9];
    const float* bhh2 = (const float*)d_in[10];

    const int P = in_sizes[0] / FD;   // 200000
    const int C = in_sizes[1] / FD;   // 50000
    const int E = P * KNB;            // 1.6M edges

    float* h_p = (float*)d_out;                  // [P*FD]
    float* h_c = h_p + (size_t)P * FD;           // [C*FD]

    // ws layout: counts[C] | cursor[C] | offsets[C+1] | elist[E] | agg[C*FD]
    char* ws = (char*)d_ws;
    int*   counts  = (int*)ws;
    int*   cursor  = counts + C;
    int*   offsets = cursor + C;
    int*   elist   = offsets + C + 1;
    // align agg to 256B
    size_t agg_off = (((size_t)(3 * C + 1 + E)) * sizeof(int) + 255) & ~(size_t)255;
    float* agg = (float*)(ws + agg_off);
    size_t needed = agg_off + (size_t)C * FD * sizeof(float);
    const bool use_csr = (ws_size >= needed);

    hipMemcpyAsync(h_p, paths,    (size_t)P * FD * sizeof(float),
                   hipMemcpyDeviceToDevice, stream);
    hipMemcpyAsync(h_c, channels, (size_t)C * FD * sizeof(float),
                   hipMemcpyDeviceToDevice, stream);

    dim3 pb(256), pg((P + 255) / 256);
    dim3 cb(256), cg((C + 255) / 256);
    dim3 eb(256), eg((E + 255) / 256);
    dim3 gb(256), gg((C * 32 + 255) / 256);

    if (use_csr) {
        hipMemsetAsync(counts, 0, (size_t)C * sizeof(int), stream);
        count_edges_kernel<<<eg, eb, 0, stream>>>(p2c, counts, E);
        scan_offsets_kernel<<<1, 1024, 0, stream>>>(counts, offsets, cursor, C);
        fill_elist_kernel<<<eg, eb, 0, stream>>>(p2c, cursor, elist, E);

        for (int it = 0; it < NITER; it++) {
            path_update_kernel<<<pg, pb, 0, stream>>>(h_c, h_p, p2c,
                                                      Wih1, Whh1, bih1, bhh1, P);
            gather_agg_kernel<<<gg, gb, 0, stream>>>(h_p, offsets, elist, agg, C);
            channel_update_kernel<<<cg, cb, 0, stream>>>(agg, h_c,
                                                         Wih2, Whh2, bih2, bhh2, C);
        }
    } else {
        float* agg0 = (float*)d_ws;   // fallback: atomic scatter, agg at ws base
        for (int it = 0; it < NITER; it++) {
            path_update_kernel<<<pg, pb, 0, stream>>>(h_c, h_p, p2c,
                                                      Wih1, Whh1, bih1, bhh1, P);
            hipMemsetAsync(agg0, 0, (size_t)C * FD * sizeof(float), stream);
            scatter_agg_atomic_kernel<<<pg, pb, 0, stream>>>(h_p, p2c, agg0, P);
            channel_update_kernel<<<cg, cb, 0, stream>>>(agg0, h_c,
                                                         Wih2, Whh2, bih2, bhh2, C);
        }
    }
}

// Round 3
// 1610.331 us; speedup vs baseline: 10.8890x; 3.3342x over previous
//
#include <hip/hip_runtime.h>

#define FD 32
#define KNB 8
#define NITER 5
#define GDIM 96   // 3*FD

typedef __bf16 bf16x8 __attribute__((ext_vector_type(8)));
typedef float  f32x4  __attribute__((ext_vector_type(4)));

__device__ __forceinline__ float sigmoidf_(float a) {
    return 1.0f / (1.0f + __expf(-a));
}
__device__ __forceinline__ float tanhf_(float a) {
    return 1.0f - 2.0f / (__expf(2.0f * a) + 1.0f);
}
__device__ __forceinline__ float bf2f(unsigned short u) {
    union { unsigned int i; float f; } v; v.i = ((unsigned int)u) << 16; return v.f;
}
__device__ __forceinline__ unsigned short f2bf(float f) {
    union { float f; unsigned int i; } v; v.f = f;
    unsigned int r = (v.i + 0x7FFFu + ((v.i >> 16) & 1u)) >> 16;
    return (unsigned short)r;
}

// ---------------- CSR build (once per launch; edge list is static) ----------

__global__ __launch_bounds__(256) void count_edges_kernel(
    const int* __restrict__ p2c, int* __restrict__ counts, int E)
{
    int e = blockIdx.x * blockDim.x + threadIdx.x;
    if (e < E) atomicAdd(&counts[p2c[e]], 1);
}

__global__ __launch_bounds__(1024) void scan_offsets_kernel(
    const int* __restrict__ counts, int* __restrict__ offsets,
    int* __restrict__ cursor, int C)
{
    __shared__ int part[1024];
    int t = threadIdx.x;
    int chunk = (C + 1023) >> 10;
    int base = t * chunk;
    int end = base + chunk; if (end > C) end = C;
    int s = 0;
    for (int i = base; i < end; i++) s += counts[i];
    part[t] = s;
    __syncthreads();
    for (int d = 1; d < 1024; d <<= 1) {
        int v = (t >= d) ? part[t - d] : 0;
        __syncthreads();
        part[t] += v;
        __syncthreads();
    }
    int run = (t == 0) ? 0 : part[t - 1];
    for (int i = base; i < end; i++) {
        offsets[i] = run;
        cursor[i] = run;
        run += counts[i];
    }
    if (t == 1023) offsets[C] = part[1023];
}

__global__ __launch_bounds__(256) void fill_elist_kernel(
    const int* __restrict__ p2c, int* __restrict__ cursor,
    int* __restrict__ elist, int E)
{
    int e = blockIdx.x * blockDim.x + threadIdx.x;
    if (e < E) {
        int c = p2c[e];
        int pos = atomicAdd(&cursor[c], 1);
        elist[pos] = e >> 3;   // path id (KNB == 8)
    }
}

// ---------------- G_c precompute: G_c = h_c @ W_ih1^T + b_ih1 ---------------

template<int GCBF>
__global__ __launch_bounds__(256) void gc_kernel(
    const float* __restrict__ h_c, void* __restrict__ Gc,
    const float* __restrict__ Wih, const float* __restrict__ bih, int C)
{
    int ch = blockIdx.x * blockDim.x + threadIdx.x;
    if (ch >= C) return;
    float x[FD];
    const float4* xr = (const float4*)(h_c + (size_t)ch * FD);
    #pragma unroll
    for (int i = 0; i < FD / 4; i++) {
        float4 v = xr[i];
        x[4*i] = v.x; x[4*i+1] = v.y; x[4*i+2] = v.z; x[4*i+3] = v.w;
    }
    #pragma unroll 4
    for (int j = 0; j < GDIM; j++) {
        float a0 = bih[j], a1 = 0.f;
        #pragma unroll
        for (int i = 0; i < FD; i += 2) {
            a0 = fmaf(Wih[j*FD + i],     x[i],     a0);
            a1 = fmaf(Wih[j*FD + i + 1], x[i + 1], a1);
        }
        float d = a0 + a1;
        if (GCBF) ((unsigned short*)Gc)[(size_t)ch * GDIM + j] = f2bf(d);
        else      ((float*)Gc)[(size_t)ch * GDIM + j] = d;
    }
}

// ---------------- MFMA path kernel ------------------------------------------
// Block = 256 threads = 4 waves; each wave owns 16 paths (no barriers at all).
// h lives in LDS (f32, padded rows); per k-step: A-frag from LDS (bf16),
// 6x mfma_f32_16x16x32_bf16 vs register-resident W_hh^T fragments, gathered
// gi from precomputed G_c (double-buffered one step ahead), gate math, h back
// to LDS.  D-layout: col = lane&15, row = (lane>>4)*4 + reg.
template<int GCBF>
__global__ __launch_bounds__(256) void path_mfma_kernel(
    float* __restrict__ h_p, const int* __restrict__ p2c,
    const void* __restrict__ Gc,
    const float* __restrict__ Whh,   // [96][32]
    const float* __restrict__ bhh,   // [96]
    int P)
{
    __shared__ float hl[64 * 36];    // 64 paths x 32 feats, pad to 36 (bank + 16B align)
    const int tid  = threadIdx.x;
    const int wid  = tid >> 6;
    const int lane = tid & 63;
    const int c    = lane & 15;
    const int kg   = lane >> 4;
    const int blk0 = blockIdx.x * 64;

    // load h rows into LDS (each wave loads exactly its own 16 rows)
    {
        int r  = tid >> 2;             // 0..63, wave-local
        int c0 = (tid & 3) * 8;
        const float4* src = (const float4*)(h_p + ((size_t)(blk0 + r)) * FD + c0);
        float4 a = src[0], b = src[1];
        float* d = &hl[r * 36 + c0];
        d[0]=a.x; d[1]=a.y; d[2]=a.z; d[3]=a.w;
        d[4]=b.x; d[5]=b.y; d[6]=b.z; d[7]=b.w;
    }

    // B fragments: B[k][n] = W_hh^T[k][16t+n] = Whh[16t+n][k]
    // lane holds B[8*kg+j][c] = Whh[16t+c][8*kg+j], j=0..7 (contiguous)
    bf16x8 Bf[6];
    #pragma unroll
    for (int t = 0; t < 6; t++) {
        const float* wr = Whh + (size_t)(16*t + c) * FD + 8*kg;
        #pragma unroll
        for (int j = 0; j < 8; j++) Bf[t][j] = (__bf16)wr[j];
    }
    float bh[6];
    #pragma unroll
    for (int t = 0; t < 6; t++) bh[t] = bhh[16*t + c];

    // neighbor indices for this lane's 4 path-rows, all 8 steps
    int idxs[4][KNB];
    #pragma unroll
    for (int q = 0; q < 4; q++) {
        int pg = blk0 + wid*16 + 4*kg + q;
        const int4* pp = (const int4*)(p2c + (size_t)pg * KNB);
        int4 u = pp[0], v = pp[1];
        idxs[q][0]=u.x; idxs[q][1]=u.y; idxs[q][2]=u.z; idxs[q][3]=u.w;
        idxs[q][4]=v.x; idxs[q][5]=v.y; idxs[q][6]=v.z; idxs[q][7]=v.w;
    }

    // gi gathers, double-buffered one step ahead
    float g[2][6][4];
    #pragma unroll
    for (int t = 0; t < 6; t++)
        #pragma unroll
        for (int q = 0; q < 4; q++) {
            if (GCBF) g[0][t][q] = bf2f(((const unsigned short*)Gc)[(size_t)idxs[q][0]*GDIM + 16*t + c]);
            else      g[0][t][q] = ((const float*)Gc)[(size_t)idxs[q][0]*GDIM + 16*t + c];
        }

    const int rowA = wid*16 + c;
    #pragma unroll
    for (int k = 0; k < KNB; k++) {
        // A fragment: lane holds h[rowA][8*kg .. 8*kg+7] as bf16
        bf16x8 Af;
        const float* ar = &hl[rowA * 36 + 8*kg];
        #pragma unroll
        for (int j = 0; j < 8; j++) Af[j] = (__bf16)ar[j];

        f32x4 acc[6];
        #pragma unroll
        for (int t = 0; t < 6; t++) {
            acc[t] = (f32x4){0.f, 0.f, 0.f, 0.f};
            acc[t] = __builtin_amdgcn_mfma_f32_16x16x32_bf16(Af, Bf[t], acc[t], 0, 0, 0);
        }

        // prefetch next step's gi while gate math runs
        if (k < KNB - 1) {
            #pragma unroll
            for (int t = 0; t < 6; t++)
                #pragma unroll
                for (int q = 0; q < 4; q++) {
                    if (GCBF) g[(k+1)&1][t][q] = bf2f(((const unsigned short*)Gc)[(size_t)idxs[q][k+1]*GDIM + 16*t + c]);
                    else      g[(k+1)&1][t][q] = ((const float*)Gc)[(size_t)idxs[q][k+1]*GDIM + 16*t + c];
                }
        }

        // gates: tiles 0,1 = r; 2,3 = z; 4,5 = n. lane covers (4 paths x 2 cols)
        #pragma unroll
        for (int q = 0; q < 4; q++) {
            int row = wid*16 + 4*kg + q;
            #pragma unroll
            for (int fi = 0; fi < 2; fi++) {
                float ghr = acc[fi][q]     + bh[fi];
                float ghz = acc[2+fi][q]   + bh[2+fi];
                float ghn = acc[4+fi][q]   + bh[4+fi];
                float r = sigmoidf_(g[k&1][fi][q]   + ghr);
                float z = sigmoidf_(g[k&1][2+fi][q] + ghz);
                float n = tanhf_(g[k&1][4+fi][q] + r * ghn);
                float* hp_ = &hl[row * 36 + c + 16*fi];
                float ho = *hp_;
                *hp_ = (1.0f - z) * n + z * ho;
            }
        }
    }

    // write h back (same wave-local mapping as the load)
    {
        int r  = tid >> 2;
        int c0 = (tid & 3) * 8;
        const float* s = &hl[r * 36 + c0];
        float4 a, b;
        a.x=s[0]; a.y=s[1]; a.z=s[2]; a.w=s[3];
        b.x=s[4]; b.y=s[5]; b.z=s[6]; b.w=s[7];
        float4* dst = (float4*)(h_p + ((size_t)(blk0 + r)) * FD + c0);
        dst[0] = a; dst[1] = b;
    }
}

// ---------------- round-2 fallback path kernel (VALU) -----------------------

__global__ __launch_bounds__(256) void path_update_kernel(
    const float* __restrict__ h_c, float* __restrict__ h_p,
    const int* __restrict__ p2c,
    const float* __restrict__ Wih, const float* __restrict__ Whh,
    const float* __restrict__ bih, const float* __restrict__ bhh, int P)
{
    int p = blockIdx.x * blockDim.x + threadIdx.x;
    if (p >= P) return;

    float h[FD];
    const float4* hp4 = (const float4*)(h_p + (size_t)p * FD);
    #pragma unroll
    for (int i = 0; i < FD / 4; i++) {
        float4 v = hp4[i];
        h[4*i] = v.x; h[4*i+1] = v.y; h[4*i+2] = v.z; h[4*i+3] = v.w;
    }

    int idx[KNB];
    const int4* pi = (const int4*)(p2c + (size_t)p * KNB);
    int4 i0 = pi[0], i1 = pi[1];
    idx[0]=i0.x; idx[1]=i0.y; idx[2]=i0.z; idx[3]=i0.w;
    idx[4]=i1.x; idx[5]=i1.y; idx[6]=i1.z; idx[7]=i1.w;

    for (int k = 0; k < KNB; k++) {
        float x[FD];
        const float4* xr = (const float4*)(h_c + (size_t)idx[k] * FD);
        #pragma unroll
        for (int i = 0; i < FD / 4; i++) {
            float4 v = xr[i];
            x[4*i] = v.x; x[4*i+1] = v.y; x[4*i+2] = v.z; x[4*i+3] = v.w;
        }

        float hn[FD];
        #pragma unroll 4
        for (int j = 0; j < FD; j++) {
            float air = bih[j],        ahr = bhh[j];
            float aiz = bih[FD + j],   ahz = bhh[FD + j];
            float ain = bih[2*FD + j], ahn = bhh[2*FD + j];
            #pragma unroll
            for (int i = 0; i < FD; i++) {
                air = fmaf(Wih[j*FD + i],          x[i], air);
                ahr = fmaf(Whh[j*FD + i],          h[i], ahr);
                aiz = fmaf(Wih[(FD + j)*FD + i],   x[i], aiz);
                ahz = fmaf(Whh[(FD + j)*FD + i],   h[i], ahz);
                ain = fmaf(Wih[(2*FD + j)*FD + i], x[i], ain);
                ahn = fmaf(Whh[(2*FD + j)*FD + i], h[i], ahn);
            }
            float r = sigmoidf_(air + ahr);
            float z = sigmoidf_(aiz + ahz);
            float n = tanhf_(ain + r * ahn);
            hn[j] = (1.0f - z) * n + z * h[j];
        }
        #pragma unroll
        for (int j = 0; j < FD; j++) h[j] = hn[j];
    }

    float4* hpw = (float4*)(h_p + (size_t)p * FD);
    #pragma unroll
    for (int i = 0; i < FD / 4; i++) {
        float4 v;
        v.x = h[4*i]; v.y = h[4*i+1]; v.z = h[4*i+2]; v.w = h[4*i+3];
        hpw[i] = v;
    }
}

__global__ __launch_bounds__(256) void scatter_agg_atomic_kernel(
    const float* __restrict__ h_p, const int* __restrict__ p2c,
    float* __restrict__ agg, int P)
{
    int p = blockIdx.x * blockDim.x + threadIdx.x;
    if (p >= P) return;
    const float* hr = h_p + (size_t)p * FD;
    #pragma unroll
    for (int k = 0; k < KNB; k++) {
        int c = p2c[(size_t)p * KNB + k];
        float* ar = agg + (size_t)c * FD;
        #pragma unroll
        for (int i = 0; i < FD; i++) atomicAdd(ar + i, hr[i]);
    }
}

// 32 lanes per channel; coalesced 128B row reads, no atomics.
__global__ __launch_bounds__(256) void gather_agg_kernel(
    const float* __restrict__ h_p, const int* __restrict__ offsets,
    const int* __restrict__ elist, float* __restrict__ agg, int C)
{
    int tid = blockIdx.x * blockDim.x + threadIdx.x;
    int c = tid >> 5;
    int feat = tid & 31;
    if (c >= C) return;
    int s = offsets[c], e = offsets[c + 1];
    float acc0 = 0.f, acc1 = 0.f;
    int i = s;
    for (; i + 2 <= e; i += 2) {
        acc0 += h_p[(size_t)elist[i]     * FD + feat];
        acc1 += h_p[(size_t)elist[i + 1] * FD + feat];
    }
    if (i < e) acc0 += h_p[(size_t)elist[i] * FD + feat];
    agg[(size_t)c * FD + feat] = acc0 + acc1;
}

__global__ __launch_bounds__(256) void channel_update_kernel(
    const float* __restrict__ agg, float* __restrict__ h_c,
    const float* __restrict__ Wih, const float* __restrict__ Whh,
    const float* __restrict__ bih, const float* __restrict__ bhh, int C)
{
    int c = blockIdx.x * blockDim.x + threadIdx.x;
    if (c >= C) return;

    float h[FD], x[FD];
    const float4* hr = (const float4*)(h_c + (size_t)c * FD);
    const float4* xr = (const float4*)(agg + (size_t)c * FD);
    #pragma unroll
    for (int i = 0; i < FD / 4; i++) {
        float4 v = hr[i];
        h[4*i] = v.x; h[4*i+1] = v.y; h[4*i+2] = v.z; h[4*i+3] = v.w;
        float4 w = xr[i];
        x[4*i] = w.x; x[4*i+1] = w.y; x[4*i+2] = w.z; x[4*i+3] = w.w;
    }

    float hn[FD];
    #pragma unroll 4
    for (int j = 0; j < FD; j++) {
        float air = bih[j],        ahr = bhh[j];
        float aiz = bih[FD + j],   ahz = bhh[FD + j];
        float ain = bih[2*FD + j], ahn = bhh[2*FD + j];
        #pragma unroll
        for (int i = 0; i < FD; i++) {
            air = fmaf(Wih[j*FD + i],          x[i], air);
            ahr = fmaf(Whh[j*FD + i],          h[i], ahr);
            aiz = fmaf(Wih[(FD + j)*FD + i],   x[i], aiz);
            ahz = fmaf(Whh[(FD + j)*FD + i],   h[i], ahz);
            ain = fmaf(Wih[(2*FD + j)*FD + i], x[i], ain);
            ahn = fmaf(Whh[(2*FD + j)*FD + i], h[i], ahn);
        }
        float r = sigmoidf_(air + ahr);
        float z = sigmoidf_(aiz + ahz);
        float n = tanhf_(ain + r * ahn);
        hn[j] = (1.0f - z) * n + z * h[j];
    }

    float4* hw = (float4*)(h_c + (size_t)c * FD);
    #pragma unroll
    for (int i = 0; i < FD / 4; i++) {
        float4 v;
        v.x = hn[4*i]; v.y = hn[4*i+1]; v.z = hn[4*i+2]; v.w = hn[4*i+3];
        hw[i] = v;
    }
}

extern "C" void kernel_launch(void* const* d_in, const int* in_sizes, int n_in,
                              void* d_out, int out_size, void* d_ws, size_t ws_size,
                              hipStream_t stream) {
    const float* paths    = (const float*)d_in[0];
    const float* channels = (const float*)d_in[1];
    const int*   p2c      = (const int*)d_in[2];
    const float* Wih1 = (const float*)d_in[3];
    const float* Whh1 = (const float*)d_in[4];
    const float* bih1 = (const float*)d_in[5];
    const float* bhh1 = (const float*)d_in[6];
    const float* Wih2 = (const float*)d_in[7];
    const float* Whh2 = (const float*)d_in[8];
    const float* bih2 = (const float*)d_in[9];
    const float* bhh2 = (const float*)d_in[10];

    const int P = in_sizes[0] / FD;   // 200000
    const int C = in_sizes[1] / FD;   // 50000
    const int E = P * KNB;            // 1.6M edges

    float* h_p = (float*)d_out;                  // [P*FD]
    float* h_c = h_p + (size_t)P * FD;           // [C*FD]

    // ws layout: counts[C] | cursor[C] | offsets[C+1] | elist[E] | shared(Gc/agg)
    char* ws = (char*)d_ws;
    int*   counts  = (int*)ws;
    int*   cursor  = counts + C;
    int*   offsets = cursor + C;
    int*   elist   = offsets + C + 1;
    size_t int_bytes = ((size_t)(3 * C + 1 + E)) * sizeof(int);
    size_t shr_off   = (int_bytes + 255) & ~(size_t)255;
    void*  shr       = (void*)(ws + shr_off);     // Gc and agg share (time-disjoint)
    float* agg       = (float*)shr;

    size_t agg_bytes  = (size_t)C * FD * sizeof(float);
    size_t need_f32   = shr_off + (size_t)C * GDIM * sizeof(float);   // >= agg
    size_t need_bf16  = shr_off + (size_t)C * GDIM * sizeof(unsigned short); // 9.6MB >= agg
    size_t need_old   = shr_off + agg_bytes;

    const bool mfma_ok = (P % 64 == 0);
    int tier;
    if      (mfma_ok && ws_size >= need_f32)  tier = 1;
    else if (mfma_ok && ws_size >= need_bf16) tier = 2;
    else if (ws_size >= need_old)             tier = 3;
    else                                      tier = 4;

    hipMemcpyAsync(h_p, paths,    (size_t)P * FD * sizeof(float),
                   hipMemcpyDeviceToDevice, stream);
    hipMemcpyAsync(h_c, channels, (size_t)C * FD * sizeof(float),
                   hipMemcpyDeviceToDevice, stream);

    dim3 pb(256), pg((P + 255) / 256);
    dim3 cb(256), cg((C + 255) / 256);
    dim3 eb(256), eg((E + 255) / 256);
    dim3 gb(256), gg((C * 32 + 255) / 256);

    if (tier <= 3) {
        hipMemsetAsync(counts, 0, (size_t)C * sizeof(int), stream);
        count_edges_kernel<<<eg, eb, 0, stream>>>(p2c, counts, E);
        scan_offsets_kernel<<<1, 1024, 0, stream>>>(counts, offsets, cursor, C);
        fill_elist_kernel<<<eg, eb, 0, stream>>>(p2c, cursor, elist, E);
    }

    if (tier == 1 || tier == 2) {
        dim3 mg(P / 64), mb(256);
        for (int it = 0; it < NITER; it++) {
            if (tier == 1) {
                gc_kernel<0><<<cg, cb, 0, stream>>>(h_c, shr, Wih1, bih1, C);
                path_mfma_kernel<0><<<mg, mb, 0, stream>>>(h_p, p2c, shr, Whh1, bhh1, P);
            } else {
                gc_kernel<1><<<cg, cb, 0, stream>>>(h_c, shr, Wih1, bih1, C);
                path_mfma_kernel<1><<<mg, mb, 0, stream>>>(h_p, p2c, shr, Whh1, bhh1, P);
            }
            gather_agg_kernel<<<gg, gb, 0, stream>>>(h_p, offsets, elist, agg, C);
            channel_update_kernel<<<cg, cb, 0, stream>>>(agg, h_c,
                                                         Wih2, Whh2, bih2, bhh2, C);
        }
    } else if (tier == 3) {
        for (int it = 0; it < NITER; it++) {
            path_update_kernel<<<pg, pb, 0, stream>>>(h_c, h_p, p2c,
                                                      Wih1, Whh1, bih1, bhh1, P);
            gather_agg_kernel<<<gg, gb, 0, stream>>>(h_p, offsets, elist, agg, C);
            channel_update_kernel<<<cg, cb, 0, stream>>>(agg, h_c,
                                                         Wih2, Whh2, bih2, bhh2, C);
        }
    } else {
        float* agg0 = (float*)d_ws;
        for (int it = 0; it < NITER; it++) {
            path_update_kernel<<<pg, pb, 0, stream>>>(h_c, h_p, p2c,
                                                      Wih1, Whh1, bih1, bhh1, P);
            hipMemsetAsync(agg0, 0, agg_bytes, stream);
            scatter_agg_atomic_kernel<<<pg, pb, 0, stream>>>(h_p, p2c, agg0, P);
            channel_update_kernel<<<cg, cb, 0, stream>>>(agg0, h_c,
                                                         Wih2, Whh2, bih2, bhh2, C);
        }
    }
}

// Round 4
// 1496.456 us; speedup vs baseline: 11.7176x; 1.0761x over previous
//
#include <hip/hip_runtime.h>

#define FD 32
#define KNB 8
#define NITER 5

typedef __bf16 bf16x8 __attribute__((ext_vector_type(8)));
typedef float  f32x4  __attribute__((ext_vector_type(4)));

__device__ __forceinline__ float sigmoidf_(float a) {
    return 1.0f / (1.0f + __expf(-a));
}
__device__ __forceinline__ float tanhf_(float a) {
    return 1.0f - 2.0f / (__expf(2.0f * a) + 1.0f);
}
__device__ __forceinline__ float bf2f(unsigned short u) {
    union { unsigned int i; float f; } v; v.i = ((unsigned int)u) << 16; return v.f;
}

// ---------------- CSR build (once per launch; edge list is static) ----------

__global__ __launch_bounds__(256) void count_edges_kernel(
    const int* __restrict__ p2c, int* __restrict__ counts, int E)
{
    int e = blockIdx.x * blockDim.x + threadIdx.x;
    if (e < E) atomicAdd(&counts[p2c[e]], 1);
}

__global__ __launch_bounds__(1024) void scan_offsets_kernel(
    const int* __restrict__ counts, int* __restrict__ offsets,
    int* __restrict__ cursor, int C)
{
    __shared__ int part[1024];
    int t = threadIdx.x;
    int chunk = (C + 1023) >> 10;
    int base = t * chunk;
    int end = base + chunk; if (end > C) end = C;
    int s = 0;
    for (int i = base; i < end; i++) s += counts[i];
    part[t] = s;
    __syncthreads();
    for (int d = 1; d < 1024; d <<= 1) {
        int v = (t >= d) ? part[t - d] : 0;
        __syncthreads();
        part[t] += v;
        __syncthreads();
    }
    int run = (t == 0) ? 0 : part[t - 1];
    for (int i = base; i < end; i++) {
        offsets[i] = run;
        cursor[i] = run;
        run += counts[i];
    }
    if (t == 1023) offsets[C] = part[1023];
}

__global__ __launch_bounds__(256) void fill_elist_kernel(
    const int* __restrict__ p2c, int* __restrict__ cursor,
    int* __restrict__ elist, int E)
{
    int e = blockIdx.x * blockDim.x + threadIdx.x;
    if (e < E) {
        int c = p2c[e];
        int pos = atomicAdd(&cursor[c], 1);
        elist[pos] = e >> 3;   // path id (KNB == 8)
    }
}

// ---------------- bf16 shadow init for h_c ----------------------------------

__global__ __launch_bounds__(256) void hc_init_kernel(
    const float* __restrict__ src, __bf16* __restrict__ dst, int n8)
{
    int i = blockIdx.x * blockDim.x + threadIdx.x;
    if (i >= n8) return;
    const float4* s = (const float4*)(src + (size_t)i * 8);
    float4 u = s[0], v = s[1];
    bf16x8 o;
    o[0]=(__bf16)u.x; o[1]=(__bf16)u.y; o[2]=(__bf16)u.z; o[3]=(__bf16)u.w;
    o[4]=(__bf16)v.x; o[5]=(__bf16)v.y; o[6]=(__bf16)v.z; o[7]=(__bf16)v.w;
    ((bf16x8*)dst)[i] = o;
}

// ---------------- fused path kernel (x-side + h-side MFMA) ------------------
// Block = 256 threads = 4 waves; wave owns 16 paths; h state in LDS (f32,
// pad-36 rows), no barriers. Per k-step:
//   A_x = h_c_bf16[p2c[p][k]] fragment (prefetched for all 8 steps up front),
//   A_h = bf16(h) from LDS,
//   r/z tiles: acc = mfma(A_x,Bx) chained with mfma(A_h,Bh)  (gi+gh summed)
//   n  tiles: separate x/h accumulators (need r * gh_n),
//   gate math on lanes (C/D layout: col=lane&15, row=(lane>>4)*4+q), h -> LDS.
// Epilogue: h_p f32 (+ optional bf16 shadow for the gather).
template<int HPS>
__global__ __launch_bounds__(256) void path_fused_kernel(
    float* __restrict__ h_p, const int* __restrict__ p2c,
    const __bf16* __restrict__ hcb,
    const float* __restrict__ Wih, const float* __restrict__ Whh,
    const float* __restrict__ bih, const float* __restrict__ bhh,
    __bf16* __restrict__ hpb)
{
    __shared__ float hl[64 * 36];
    const int tid  = threadIdx.x;
    const int wid  = tid >> 6;
    const int lane = tid & 63;
    const int c    = lane & 15;
    const int kg   = lane >> 4;
    const int blk0 = blockIdx.x * 64;

    // stage h rows (wave-local: wave w touches rows 16w..16w+15 only)
    {
        int r  = tid >> 2;
        int c0 = (tid & 3) * 8;
        const float4* src = (const float4*)(h_p + ((size_t)(blk0 + r)) * FD + c0);
        float4 a = src[0], b = src[1];
        float* d = &hl[r * 36 + c0];
        d[0]=a.x; d[1]=a.y; d[2]=a.z; d[3]=a.w;
        d[4]=b.x; d[5]=b.y; d[6]=b.z; d[7]=b.w;
    }

    // B fragments: B[k][n] = W[n][k]; lane holds W[16t+c][8kg..8kg+7]
    bf16x8 Bx[6], Bh[6];
    #pragma unroll
    for (int t = 0; t < 6; t++) {
        const float* wi = Wih + (size_t)(16*t + c) * FD + 8*kg;
        const float* wh = Whh + (size_t)(16*t + c) * FD + 8*kg;
        #pragma unroll
        for (int j = 0; j < 8; j++) {
            Bx[t][j] = (__bf16)wi[j];
            Bh[t][j] = (__bf16)wh[j];
        }
    }
    float bsum[4], bin[2], bhn[2];
    #pragma unroll
    for (int t = 0; t < 4; t++) bsum[t] = bih[16*t + c] + bhh[16*t + c];
    #pragma unroll
    for (int fi = 0; fi < 2; fi++) {
        bin[fi] = bih[64 + 16*fi + c];
        bhn[fi] = bhh[64 + 16*fi + c];
    }

    // prefetch ALL 8 steps' x-fragments (h_c frozen during the path sweep)
    const int pA = blk0 + wid*16 + c;
    const int4* pp = (const int4*)(p2c + (size_t)pA * KNB);
    int4 ia = pp[0], ib = pp[1];
    int idxA[KNB] = {ia.x, ia.y, ia.z, ia.w, ib.x, ib.y, ib.z, ib.w};
    bf16x8 Ax[KNB];
    #pragma unroll
    for (int k = 0; k < KNB; k++)
        Ax[k] = *(const bf16x8*)(hcb + (size_t)idxA[k] * FD + 8*kg);

    const int rowA = wid*16 + c;
    #pragma unroll
    for (int k = 0; k < KNB; k++) {
        bf16x8 Ah;
        const float* ar = &hl[rowA * 36 + 8*kg];
        #pragma unroll
        for (int j = 0; j < 8; j++) Ah[j] = (__bf16)ar[j];

        const f32x4 z4 = {0.f, 0.f, 0.f, 0.f};
        f32x4 arz[4], xn[2], hn[2];
        #pragma unroll
        for (int t = 0; t < 4; t++) {
            arz[t] = __builtin_amdgcn_mfma_f32_16x16x32_bf16(Ax[k], Bx[t], z4, 0, 0, 0);
            arz[t] = __builtin_amdgcn_mfma_f32_16x16x32_bf16(Ah,    Bh[t], arz[t], 0, 0, 0);
        }
        #pragma unroll
        for (int fi = 0; fi < 2; fi++) {
            xn[fi] = __builtin_amdgcn_mfma_f32_16x16x32_bf16(Ax[k], Bx[4+fi], z4, 0, 0, 0);
            hn[fi] = __builtin_amdgcn_mfma_f32_16x16x32_bf16(Ah,    Bh[4+fi], z4, 0, 0, 0);
        }

        #pragma unroll
        for (int q = 0; q < 4; q++) {
            float* hrow = &hl[(wid*16 + 4*kg + q) * 36];
            #pragma unroll
            for (int fi = 0; fi < 2; fi++) {
                float r = sigmoidf_(arz[fi][q]   + bsum[fi]);
                float z = sigmoidf_(arz[2+fi][q] + bsum[2+fi]);
                float n = tanhf_(xn[fi][q] + bin[fi] + r * (hn[fi][q] + bhn[fi]));
                float ho = hrow[c + 16*fi];
                hrow[c + 16*fi] = (1.0f - z) * n + z * ho;
            }
        }
    }

    // epilogue: f32 h_p + optional bf16 shadow
    {
        int r  = tid >> 2;
        int c0 = (tid & 3) * 8;
        const float* s = &hl[r * 36 + c0];
        float4 a, b;
        a.x=s[0]; a.y=s[1]; a.z=s[2]; a.w=s[3];
        b.x=s[4]; b.y=s[5]; b.z=s[6]; b.w=s[7];
        float4* dst = (float4*)(h_p + ((size_t)(blk0 + r)) * FD + c0);
        dst[0] = a; dst[1] = b;
        if (HPS) {
            bf16x8 o;
            o[0]=(__bf16)a.x; o[1]=(__bf16)a.y; o[2]=(__bf16)a.z; o[3]=(__bf16)a.w;
            o[4]=(__bf16)b.x; o[5]=(__bf16)b.y; o[6]=(__bf16)b.z; o[7]=(__bf16)b.w;
            *(bf16x8*)(hpb + ((size_t)(blk0 + r)) * FD + c0) = o;
        }
    }
}

// ---------------- round-2 fallback path kernel (VALU) -----------------------

__global__ __launch_bounds__(256) void path_update_kernel(
    const float* __restrict__ h_c, float* __restrict__ h_p,
    const int* __restrict__ p2c,
    const float* __restrict__ Wih, const float* __restrict__ Whh,
    const float* __restrict__ bih, const float* __restrict__ bhh, int P)
{
    int p = blockIdx.x * blockDim.x + threadIdx.x;
    if (p >= P) return;

    float h[FD];
    const float4* hp4 = (const float4*)(h_p + (size_t)p * FD);
    #pragma unroll
    for (int i = 0; i < FD / 4; i++) {
        float4 v = hp4[i];
        h[4*i] = v.x; h[4*i+1] = v.y; h[4*i+2] = v.z; h[4*i+3] = v.w;
    }

    int idx[KNB];
    const int4* pi = (const int4*)(p2c + (size_t)p * KNB);
    int4 i0 = pi[0], i1 = pi[1];
    idx[0]=i0.x; idx[1]=i0.y; idx[2]=i0.z; idx[3]=i0.w;
    idx[4]=i1.x; idx[5]=i1.y; idx[6]=i1.z; idx[7]=i1.w;

    for (int k = 0; k < KNB; k++) {
        float x[FD];
        const float4* xr = (const float4*)(h_c + (size_t)idx[k] * FD);
        #pragma unroll
        for (int i = 0; i < FD / 4; i++) {
            float4 v = xr[i];
            x[4*i] = v.x; x[4*i+1] = v.y; x[4*i+2] = v.z; x[4*i+3] = v.w;
        }

        float hn[FD];
        #pragma unroll 4
        for (int j = 0; j < FD; j++) {
            float air = bih[j],        ahr = bhh[j];
            float aiz = bih[FD + j],   ahz = bhh[FD + j];
            float ain = bih[2*FD + j], ahn = bhh[2*FD + j];
            #pragma unroll
            for (int i = 0; i < FD; i++) {
                air = fmaf(Wih[j*FD + i],          x[i], air);
                ahr = fmaf(Whh[j*FD + i],          h[i], ahr);
                aiz = fmaf(Wih[(FD + j)*FD + i],   x[i], aiz);
                ahz = fmaf(Whh[(FD + j)*FD + i],   h[i], ahz);
                ain = fmaf(Wih[(2*FD + j)*FD + i], x[i], ain);
                ahn = fmaf(Whh[(2*FD + j)*FD + i], h[i], ahn);
            }
            float r = sigmoidf_(air + ahr);
            float z = sigmoidf_(aiz + ahz);
            float n = tanhf_(ain + r * ahn);
            hn[j] = (1.0f - z) * n + z * h[j];
        }
        #pragma unroll
        for (int j = 0; j < FD; j++) h[j] = hn[j];
    }

    float4* hpw = (float4*)(h_p + (size_t)p * FD);
    #pragma unroll
    for (int i = 0; i < FD / 4; i++) {
        float4 v;
        v.x = h[4*i]; v.y = h[4*i+1]; v.z = h[4*i+2]; v.w = h[4*i+3];
        hpw[i] = v;
    }
}

__global__ __launch_bounds__(256) void scatter_agg_atomic_kernel(
    const float* __restrict__ h_p, const int* __restrict__ p2c,
    float* __restrict__ agg, int P)
{
    int p = blockIdx.x * blockDim.x + threadIdx.x;
    if (p >= P) return;
    const float* hr = h_p + (size_t)p * FD;
    #pragma unroll
    for (int k = 0; k < KNB; k++) {
        int c = p2c[(size_t)p * KNB + k];
        float* ar = agg + (size_t)c * FD;
        #pragma unroll
        for (int i = 0; i < FD; i++) atomicAdd(ar + i, hr[i]);
    }
}

// 32 lanes per channel; coalesced row reads, no atomics. GBF: bf16 shadow src.
template<int GBF>
__global__ __launch_bounds__(256) void gather_agg_kernel(
    const void* __restrict__ hsrc, const int* __restrict__ offsets,
    const int* __restrict__ elist, float* __restrict__ agg, int C)
{
    int tid = blockIdx.x * blockDim.x + threadIdx.x;
    int c = tid >> 5;
    int feat = tid & 31;
    if (c >= C) return;
    int s = offsets[c], e = offsets[c + 1];
    float acc0 = 0.f, acc1 = 0.f;
    int i = s;
    if (GBF) {
        const unsigned short* hb = (const unsigned short*)hsrc;
        for (; i + 2 <= e; i += 2) {
            acc0 += bf2f(hb[(size_t)elist[i]     * FD + feat]);
            acc1 += bf2f(hb[(size_t)elist[i + 1] * FD + feat]);
        }
        if (i < e) acc0 += bf2f(hb[(size_t)elist[i] * FD + feat]);
    } else {
        const float* hf = (const float*)hsrc;
        for (; i + 2 <= e; i += 2) {
            acc0 += hf[(size_t)elist[i]     * FD + feat];
            acc1 += hf[(size_t)elist[i + 1] * FD + feat];
        }
        if (i < e) acc0 += hf[(size_t)elist[i] * FD + feat];
    }
    agg[(size_t)c * FD + feat] = acc0 + acc1;
}

// One thread per channel: h_c = GRU2(agg, h_c); optional bf16 shadow write.
template<int WSH>
__global__ __launch_bounds__(256) void channel_update_kernel(
    const float* __restrict__ agg, float* __restrict__ h_c,
    const float* __restrict__ Wih, const float* __restrict__ Whh,
    const float* __restrict__ bih, const float* __restrict__ bhh,
    __bf16* __restrict__ hcb, int C)
{
    int c = blockIdx.x * blockDim.x + threadIdx.x;
    if (c >= C) return;

    float h[FD], x[FD];
    const float4* hr = (const float4*)(h_c + (size_t)c * FD);
    const float4* xr = (const float4*)(agg + (size_t)c * FD);
    #pragma unroll
    for (int i = 0; i < FD / 4; i++) {
        float4 v = hr[i];
        h[4*i] = v.x; h[4*i+1] = v.y; h[4*i+2] = v.z; h[4*i+3] = v.w;
        float4 w = xr[i];
        x[4*i] = w.x; x[4*i+1] = w.y; x[4*i+2] = w.z; x[4*i+3] = w.w;
    }

    float hn[FD];
    #pragma unroll 4
    for (int j = 0; j < FD; j++) {
        float air = bih[j],        ahr = bhh[j];
        float aiz = bih[FD + j],   ahz = bhh[FD + j];
        float ain = bih[2*FD + j], ahn = bhh[2*FD + j];
        #pragma unroll
        for (int i = 0; i < FD; i++) {
            air = fmaf(Wih[j*FD + i],          x[i], air);
            ahr = fmaf(Whh[j*FD + i],          h[i], ahr);
            aiz = fmaf(Wih[(FD + j)*FD + i],   x[i], aiz);
            ahz = fmaf(Whh[(FD + j)*FD + i],   h[i], ahz);
            ain = fmaf(Wih[(2*FD + j)*FD + i], x[i], ain);
            ahn = fmaf(Whh[(2*FD + j)*FD + i], h[i], ahn);
        }
        float r = sigmoidf_(air + ahr);
        float z = sigmoidf_(aiz + ahz);
        float n = tanhf_(ain + r * ahn);
        hn[j] = (1.0f - z) * n + z * h[j];
    }

    float4* hw = (float4*)(h_c + (size_t)c * FD);
    #pragma unroll
    for (int i = 0; i < FD / 4; i++) {
        float4 v;
        v.x = hn[4*i]; v.y = hn[4*i+1]; v.z = hn[4*i+2]; v.w = hn[4*i+3];
        hw[i] = v;
    }
    if (WSH) {
        #pragma unroll
        for (int g = 0; g < 4; g++) {
            bf16x8 o;
            #pragma unroll
            for (int j = 0; j < 8; j++) o[j] = (__bf16)hn[8*g + j];
            *(bf16x8*)(hcb + (size_t)c * FD + 8*g) = o;
        }
    }
}

extern "C" void kernel_launch(void* const* d_in, const int* in_sizes, int n_in,
                              void* d_out, int out_size, void* d_ws, size_t ws_size,
                              hipStream_t stream) {
    const float* paths    = (const float*)d_in[0];
    const float* channels = (const float*)d_in[1];
    const int*   p2c      = (const int*)d_in[2];
    const float* Wih1 = (const float*)d_in[3];
    const float* Whh1 = (const float*)d_in[4];
    const float* bih1 = (const float*)d_in[5];
    const float* bhh1 = (const float*)d_in[6];
    const float* Wih2 = (const float*)d_in[7];
    const float* Whh2 = (const float*)d_in[8];
    const float* bih2 = (const float*)d_in[9];
    const float* bhh2 = (const float*)d_in[10];

    const int P = in_sizes[0] / FD;   // 200000
    const int C = in_sizes[1] / FD;   // 50000
    const int E = P * KNB;            // 1.6M edges

    float* h_p = (float*)d_out;                  // [P*FD]
    float* h_c = h_p + (size_t)P * FD;           // [C*FD]

    // ws layout: counts[C] | cursor[C] | offsets[C+1] | elist[E] | agg | hc_bf | hp_bf
    char* ws = (char*)d_ws;
    int*   counts  = (int*)ws;
    int*   cursor  = counts + C;
    int*   offsets = cursor + C;
    int*   elist   = offsets + C + 1;
    size_t int_bytes = ((size_t)(3 * C + 1 + E)) * sizeof(int);
    size_t agg_off  = (int_bytes + 255) & ~(size_t)255;
    size_t agg_b    = (size_t)C * FD * sizeof(float);
    size_t hcb_off  = (agg_off + agg_b + 255) & ~(size_t)255;
    size_t hcb_b    = (size_t)C * FD * sizeof(unsigned short);
    size_t hpb_off  = (hcb_off + hcb_b + 255) & ~(size_t)255;
    size_t hpb_b    = (size_t)P * FD * sizeof(unsigned short);

    float*  agg = (float*)(ws + agg_off);
    __bf16* hcb = (__bf16*)(ws + hcb_off);
    __bf16* hpb = (__bf16*)(ws + hpb_off);

    const bool mfma_ok = (P % 64 == 0) && ((C * FD) % 8 == 0);
    int tier;
    if      (mfma_ok && ws_size >= hpb_off + hpb_b) tier = 1;  // + hp bf16 shadow
    else if (mfma_ok && ws_size >= hcb_off + hcb_b) tier = 2;  // hc shadow only
    else if (ws_size >= agg_off + agg_b)            tier = 3;  // round-2 path
    else                                            tier = 4;  // atomic fallback

    hipMemcpyAsync(h_p, paths,    (size_t)P * FD * sizeof(float),
                   hipMemcpyDeviceToDevice, stream);
    hipMemcpyAsync(h_c, channels, (size_t)C * FD * sizeof(float),
                   hipMemcpyDeviceToDevice, stream);

    dim3 pb(256), pg((P + 255) / 256);
    dim3 cb(256), cg((C + 255) / 256);
    dim3 eb(256), eg((E + 255) / 256);
    dim3 gb(256), gg((C * 32 + 255) / 256);

    if (tier <= 3) {
        hipMemsetAsync(counts, 0, (size_t)C * sizeof(int), stream);
        count_edges_kernel<<<eg, eb, 0, stream>>>(p2c, counts, E);
        scan_offsets_kernel<<<1, 1024, 0, stream>>>(counts, offsets, cursor, C);
        fill_elist_kernel<<<eg, eb, 0, stream>>>(p2c, cursor, elist, E);
    }

    if (tier == 1 || tier == 2) {
        int n8 = C * FD / 8;
        hc_init_kernel<<<(n8 + 255) / 256, 256, 0, stream>>>(channels, hcb, n8);
        dim3 mg(P / 64), mb(256);
        for (int it = 0; it < NITER; it++) {
            if (tier == 1) {
                path_fused_kernel<1><<<mg, mb, 0, stream>>>(h_p, p2c, hcb,
                                                            Wih1, Whh1, bih1, bhh1, hpb);
                gather_agg_kernel<1><<<gg, gb, 0, stream>>>(hpb, offsets, elist, agg, C);
            } else {
                path_fused_kernel<0><<<mg, mb, 0, stream>>>(h_p, p2c, hcb,
                                                            Wih1, Whh1, bih1, bhh1, nullptr);
                gather_agg_kernel<0><<<gg, gb, 0, stream>>>(h_p, offsets, elist, agg, C);
            }
            channel_update_kernel<1><<<cg, cb, 0, stream>>>(agg, h_c,
                                                            Wih2, Whh2, bih2, bhh2, hcb, C);
        }
    } else if (tier == 3) {
        for (int it = 0; it < NITER; it++) {
            path_update_kernel<<<pg, pb, 0, stream>>>(h_c, h_p, p2c,
                                                      Wih1, Whh1, bih1, bhh1, P);
            gather_agg_kernel<0><<<gg, gb, 0, stream>>>(h_p, offsets, elist, agg, C);
            channel_update_kernel<0><<<cg, cb, 0, stream>>>(agg, h_c,
                                                            Wih2, Whh2, bih2, bhh2, nullptr, C);
        }
    } else {
        float* agg0 = (float*)d_ws;
        for (int it = 0; it < NITER; it++) {
            path_update_kernel<<<pg, pb, 0, stream>>>(h_c, h_p, p2c,
                                                      Wih1, Whh1, bih1, bhh1, P);
            hipMemsetAsync(agg0, 0, agg_b, stream);
            scatter_agg_atomic_kernel<<<pg, pb, 0, stream>>>(h_p, p2c, agg0, P);
            channel_update_kernel<0><<<cg, cb, 0, stream>>>(agg0, h_c,
                                                            Wih2, Whh2, bih2, bhh2, nullptr, C);
        }
    }
}